// Round 1
// baseline (221.479 us; speedup 1.0000x reference)
//
#include <hip/hip_runtime.h>
#include <math.h>

#define B_  64
#define T_  1024
#define QD_ 1024
#define CD_ 512

// ---------------------------------------------------------------------------
// Kernel A: normalized attention weights a[b,t]
//   raw = ((1-u)*alpha[t] + u*alpha[t-1] + 1e-6)^sq ;  a = raw / sum_t(raw)
// One block per batch, 256 threads, 4 t's per thread (float4).
// ---------------------------------------------------------------------------
__global__ __launch_bounds__(256) void attn_alpha_kernel(
    const float* __restrict__ alpha, const float* __restrict__ u,
    const float* __restrict__ sq, float* __restrict__ out_a)
{
    const int b   = blockIdx.x;
    const int tid = threadIdx.x;
    __shared__ float s_alpha[T_];
    __shared__ float s_red[4];

    ((float4*)s_alpha)[tid] = ((const float4*)(alpha + (size_t)b * T_))[tid];
    __syncthreads();

    const float ub  = u[b];
    const float sqb = sq[b];
    const float omu = 1.0f - ub;

    const int t0 = tid * 4;
    float raw[4];
    float lsum = 0.f;
#pragma unroll
    for (int i = 0; i < 4; ++i) {
        const int t = t0 + i;
        const float prev = (t == 0) ? 0.f : s_alpha[t - 1];
        const float x = omu * s_alpha[t] + ub * prev + 1e-6f;
        const float r = powf(x, sqb);
        raw[i] = r;
        lsum += r;
    }
    // wave (64-lane) reduce
#pragma unroll
    for (int off = 32; off > 0; off >>= 1) lsum += __shfl_down(lsum, off);
    if ((tid & 63) == 0) s_red[tid >> 6] = lsum;
    __syncthreads();
    if (tid == 0) s_red[0] = s_red[0] + s_red[1] + s_red[2] + s_red[3];
    __syncthreads();
    const float inv = 1.0f / s_red[0];

    float4 o;
    o.x = raw[0] * inv; o.y = raw[1] * inv; o.z = raw[2] * inv; o.w = raw[3] * inv;
    ((float4*)(out_a + (size_t)b * T_))[tid] = o;
}

// ---------------------------------------------------------------------------
// Kernel B: context partials.  grid = (S segments, B batches), 128 threads.
// Thread tid owns float4 lane of CD (128*4 = 512).  Each block accumulates
// seg_len timesteps and writes one [CD] partial row to ws.
// ---------------------------------------------------------------------------
__global__ __launch_bounds__(128) void attn_ctx_partial(
    const float* __restrict__ inputs, const float* __restrict__ a,
    float* __restrict__ part, int S, int seg_len)
{
    const int seg = blockIdx.x;
    const int b   = blockIdx.y;
    const int tid = threadIdx.x;

    __shared__ float s_a[T_];
    const float* ab = a + (size_t)b * T_ + (size_t)seg * seg_len;
    for (int i = tid; i < seg_len; i += 128) s_a[i] = ab[i];
    __syncthreads();

    const float4* in4 =
        (const float4*)(inputs + ((size_t)b * T_ + (size_t)seg * seg_len) * CD_);

    float4 acc = {0.f, 0.f, 0.f, 0.f};
#pragma unroll 8
    for (int i = 0; i < seg_len; ++i) {
        const float av = s_a[i];
        const float4 x = in4[(size_t)i * 128 + tid];
        acc.x += av * x.x; acc.y += av * x.y; acc.z += av * x.z; acc.w += av * x.w;
    }
    ((float4*)(part + ((size_t)b * S + seg) * CD_))[tid] = acc;
}

// Atomic fallback (used only if d_ws is too small for even one partial set).
__global__ __launch_bounds__(128) void attn_ctx_atomic(
    const float* __restrict__ inputs, const float* __restrict__ a,
    float* __restrict__ ctx, int S, int seg_len)
{
    const int seg = blockIdx.x;
    const int b   = blockIdx.y;
    const int tid = threadIdx.x;

    __shared__ float s_a[T_];
    const float* ab = a + (size_t)b * T_ + (size_t)seg * seg_len;
    for (int i = tid; i < seg_len; i += 128) s_a[i] = ab[i];
    __syncthreads();

    const float4* in4 =
        (const float4*)(inputs + ((size_t)b * T_ + (size_t)seg * seg_len) * CD_);

    float4 acc = {0.f, 0.f, 0.f, 0.f};
#pragma unroll 8
    for (int i = 0; i < seg_len; ++i) {
        const float av = s_a[i];
        const float4 x = in4[(size_t)i * 128 + tid];
        acc.x += av * x.x; acc.y += av * x.y; acc.z += av * x.z; acc.w += av * x.w;
    }
    float* dst = ctx + (size_t)b * CD_ + tid * 4;
    atomicAdd(dst + 0, acc.x);
    atomicAdd(dst + 1, acc.y);
    atomicAdd(dst + 2, acc.z);
    atomicAdd(dst + 3, acc.w);
}

// ---------------------------------------------------------------------------
// Kernel C: reduce partials -> context; then the two 1536-element dots:
//   ta = [context (512), query (1024)];  u_new = sigmoid(ta.W_u + b_u)
//   sq_new = sigmoid(ta.W_sq + b_sq) + 1
// One block per batch, 512 threads (thread == context channel).
// ---------------------------------------------------------------------------
__global__ __launch_bounds__(512) void attn_final(
    const float* __restrict__ part, int S,
    const float* __restrict__ query,
    const float* __restrict__ W_u, const float* __restrict__ b_u,
    const float* __restrict__ W_sq, const float* __restrict__ b_sq,
    float* __restrict__ out_ctx, float* __restrict__ out_u,
    float* __restrict__ out_sq, int use_ws)
{
    const int b   = blockIdx.x;
    const int tid = threadIdx.x;   // 0..511 == context channel

    float c;
    if (use_ws) {
        c = 0.f;
        for (int s = 0; s < S; ++s)
            c += part[((size_t)b * S + s) * CD_ + tid];
        out_ctx[(size_t)b * CD_ + tid] = c;
    } else {
        c = out_ctx[(size_t)b * CD_ + tid];  // atomic path already wrote it
    }

    const float* qb = query + (size_t)b * QD_;
    const float q0 = qb[tid];
    const float q1 = qb[tid + 512];

    float du = c * W_u[tid]  + q0 * W_u[512 + tid]  + q1 * W_u[1024 + tid];
    float ds = c * W_sq[tid] + q0 * W_sq[512 + tid] + q1 * W_sq[1024 + tid];

#pragma unroll
    for (int off = 32; off > 0; off >>= 1) {
        du += __shfl_down(du, off);
        ds += __shfl_down(ds, off);
    }
    __shared__ float s_u[8], s_s[8];
    if ((tid & 63) == 0) { s_u[tid >> 6] = du; s_s[tid >> 6] = ds; }
    __syncthreads();
    if (tid == 0) {
        float su = 0.f, ss = 0.f;
#pragma unroll
        for (int w = 0; w < 8; ++w) { su += s_u[w]; ss += s_s[w]; }
        su += b_u[0];
        ss += b_sq[0];
        out_u[b]  = 1.0f / (1.0f + expf(-su));
        out_sq[b] = 1.0f / (1.0f + expf(-ss)) + 1.0f;
    }
}

// ---------------------------------------------------------------------------
extern "C" void kernel_launch(void* const* d_in, const int* in_sizes, int n_in,
                              void* d_out, int out_size, void* d_ws, size_t ws_size,
                              hipStream_t stream) {
    const float* query  = (const float*)d_in[0];  // [B,1,QD]
    const float* inputs = (const float*)d_in[1];  // [B,T,CD]
    const float* alpha  = (const float*)d_in[2];  // [B,T]
    const float* u      = (const float*)d_in[3];  // [B,1]
    const float* sq     = (const float*)d_in[4];  // [B,1]
    const float* W_u    = (const float*)d_in[5];  // [QD+CD,1]
    const float* b_u    = (const float*)d_in[6];  // [1]
    const float* W_sq   = (const float*)d_in[7];  // [QD+CD,1]
    const float* b_sq   = (const float*)d_in[8];  // [1]

    float* out      = (float*)d_out;
    float* out_ctx  = out;                         // [B,CD]
    float* out_a    = out + (size_t)B_ * CD_;      // [B,T]
    float* out_u    = out_a + (size_t)B_ * T_;     // [B]
    float* out_sq   = out_u + B_;                  // [B]

    // 1) normalized attention weights
    attn_alpha_kernel<<<B_, 256, 0, stream>>>(alpha, u, sq, out_a);

    // 2) context reduction — pick segment count S that fits d_ws
    int S = 32;
    while (S > 1 && ws_size < (size_t)B_ * S * CD_ * sizeof(float)) S >>= 1;
    const int use_ws = (ws_size >= (size_t)B_ * S * CD_ * sizeof(float)) ? 1 : 0;
    const int seg_len = T_ / S;
    float* part = (float*)d_ws;

    if (use_ws) {
        attn_ctx_partial<<<dim3(S, B_), 128, 0, stream>>>(inputs, out_a, part, S, seg_len);
    } else {
        hipMemsetAsync(out_ctx, 0, (size_t)B_ * CD_ * sizeof(float), stream);
        attn_ctx_atomic<<<dim3(S, B_), 128, 0, stream>>>(inputs, out_a, out_ctx, S, seg_len);
    }

    // 3) final reduce + heads
    attn_final<<<B_, 512, 0, stream>>>(part, S, query, W_u, b_u, W_sq, b_sq,
                                       out_ctx, out_u, out_sq, use_ws);
}